// Round 10
// baseline (166.142 us; speedup 1.0000x reference)
//
#include <hip/hip_runtime.h>

#define NEGF -1000000000.0f
#define LOG2E 1.4426950408889634f
#define LN2 0.6931471805599453f

constexpr int Bn = 64;
constexpr int Tn = 1000;
constexpr int Un = 250;
constexpr int RING_GRPS = 12;   // ring capacity in 8-row groups (12*8KB = 96KB LDS)

// gfx950-native base-2 transcendentals: v_exp_f32 is 2^x, v_log_f32 is log2(x)
__device__ __forceinline__ float exp2fast(float x) { return __builtin_amdgcn_exp2f(x); }
__device__ __forceinline__ float log2fast(float x) { return __builtin_amdgcn_logf(x); }

// ---------------------------------------------------------------------------
// DPP cross-lane ops (gfx9-lineage controls, retained on CDNA4).
//   wave_shr:1 (0x138) + bound_ctrl=1: lane i <- lane i-1, lane 0 <- 0.
//   Reductions: row_shr 1/2/4/8 + row_bcast:15/31, result in lane 63.
// ---------------------------------------------------------------------------
template <int CTRL>
__device__ __forceinline__ float dppmov(float x) {
    return __int_as_float(__builtin_amdgcn_update_dpp(
        0, __float_as_int(x), CTRL, 0xf, 0xf, true));
}
__device__ __forceinline__ float dpp_wave_shr1(float x) { return dppmov<0x138>(x); }

__device__ __forceinline__ float wave_red_max(float x) {  // = max(max_x, 0)
    x = fmaxf(x, dppmov<0x111>(x));
    x = fmaxf(x, dppmov<0x112>(x));
    x = fmaxf(x, dppmov<0x114>(x));
    x = fmaxf(x, dppmov<0x118>(x));
    x = fmaxf(x, dppmov<0x142>(x));
    x = fmaxf(x, dppmov<0x143>(x));
    return __int_as_float(__builtin_amdgcn_readlane(__float_as_int(x), 63));
}
__device__ __forceinline__ float wave_red_sum(float x) {
    x += dppmov<0x111>(x);
    x += dppmov<0x112>(x);
    x += dppmov<0x114>(x);
    x += dppmov<0x118>(x);
    x += dppmov<0x142>(x);
    x += dppmov<0x143>(x);
    return __int_as_float(__builtin_amdgcn_readlane(__float_as_int(x), 63));
}

typedef float v2f __attribute__((ext_vector_type(2)));

// ---------------------------------------------------------------------------
// Producer load machinery: PROVEN 16-slot pipeline (32 dwordx2 in flight,
// per-slot register-tied vmcnt(30)). Each producer owns every 3rd group of 8
// rows; slot j's next use is 2 of its groups (= +48 rows) later.
// readfirstlane: row index is wave-uniform by construction, but derives from
// threadIdx-based wid, so the compiler can't prove it — force SGPR for the
// "s" saddr constraint (round-9 compile failure).
// ---------------------------------------------------------------------------
#define PREFILL(J, T)                                                         \
    {                                                                         \
        int tl_ = (T) <= last ? (T) : last;                                   \
        tl_ = __builtin_amdgcn_readfirstlane(tl_);                            \
        const char* rowp_ = pbase + (size_t)tl_ * 1000;                       \
        asm volatile("global_load_dwordx2 %0, %1, %2"                         \
                     : "=v"(lo[J]) : "v"(voff_lo), "s"(rowp_));               \
        asm volatile("global_load_dwordx2 %0, %1, %2"                         \
                     : "=v"(hi[J]) : "v"(voff_hi), "s"(rowp_));               \
    }

// One producer row: wait slot, q = exp2(fma(logit,LOG2E,bias)) (bit-identical
// to the proven inline form; masked cols -> 0), ds_write into the ring,
// zacc += row's log2 softmax denominator, refill slot (+48 rows ahead).
#define PROW(SLOT, J)                                                         \
    {                                                                         \
        asm volatile("s_waitcnt vmcnt(30)"                                    \
                     : "+v"(lo[SLOT]), "+v"(hi[SLOT]));                       \
        float q0 = exp2fast(__builtin_fmaf(lo[SLOT].x, LOG2E, bias0));        \
        float q1 = exp2fast(__builtin_fmaf(lo[SLOT].y, LOG2E, bias1));        \
        float q2 = exp2fast(__builtin_fmaf(hi[SLOT].x, LOG2E, bias2));        \
        float q3 = exp2fast(__builtin_fmaf(hi[SLOT].y, LOG2E, bias3));        \
        int row_ = 8 * g + (J);                                               \
        if (row_ < n_t) {                                                     \
            float4 qv_; qv_.x = q0; qv_.y = q1; qv_.z = q2; qv_.w = q3;       \
            *(float4*)(rb_ + (J) * 256) = qv_;                                \
            float rs_ = wave_red_sum((q0 + q1) + (q2 + q3));                  \
            zacc += log2fast(QB + rs_);                                       \
        }                                                                     \
        PREFILL(SLOT, row_ + 48);                                             \
    }

// One producer group: ring-reuse guard, 8 rows, then lgkmcnt-drain + release
// flag so the consumer can read the data.
#define PGRP(SB)                                                              \
    {                                                                         \
        if (g >= RING_GRPS) {                                                 \
            while (__hip_atomic_load(&cons_done, __ATOMIC_ACQUIRE,            \
                       __HIP_MEMORY_SCOPE_WORKGROUP) < g - RING_GRPS + 1)     \
                __builtin_amdgcn_s_sleep(1);                                  \
        }                                                                     \
        float* rb_ = &ring[(size_t)(g % RING_GRPS) * 2048 + lane * 4];        \
        PROW(SB + 0, 0); PROW(SB + 1, 1); PROW(SB + 2, 2); PROW(SB + 3, 3);   \
        PROW(SB + 4, 4); PROW(SB + 5, 5); PROW(SB + 6, 6); PROW(SB + 7, 7);   \
        asm volatile("s_waitcnt lgkmcnt(0)" ::: "memory");                    \
        __hip_atomic_store(&ready[g % RING_GRPS], g + 1, __ATOMIC_RELEASE,    \
                           __HIP_MEMORY_SCOPE_WORKGROUP);                     \
    }

// Consumer step: one ds_read_b128 of precomputed q + the alpha update.
// Identical arithmetic/order to the proven STEP_Q.
#define CSTEP(J)                                                              \
    {                                                                         \
        float4 qv_ = *(const float4*)(rb_ + (J) * 256);                       \
        float p7 = dpp_wave_shr1(a7); /* old a7 of lane-1; lane0 -> 0 */      \
        float s65 = a6 + a5, s43 = a4 + a3, s21 = a2 + a1, s0p = a0 + p7;     \
        a7 = (a7 + s65) * qv_.w;  a6 = s65 * QB;                              \
        a5 = (a5 + s43) * qv_.z;  a4 = s43 * QB;                              \
        a3 = (a3 + s21) * qv_.y;  a2 = s21 * QB;                              \
        a1 = (a1 + s0p) * qv_.x;  a0 = s0p * QB;                              \
    }

#define RENORM()                                                              \
    {                                                                         \
        float mx = fmaxf(fmaxf(fmaxf(a0, a1), fmaxf(a2, a3)),                 \
                         fmaxf(fmaxf(a4, a5), fmaxf(a6, a7)));                \
        mx = wave_red_max(mx); /* alphas >= 0, mx > 0 always */               \
        int e_ = (int)((__float_as_uint(mx) >> 23) & 255) - 127;              \
        float scale_ = __uint_as_float((unsigned)(127 - e_) << 23);           \
        a0 *= scale_; a1 *= scale_; a2 *= scale_; a3 *= scale_;               \
        a4 *= scale_; a5 *= scale_; a6 *= scale_; a7 *= scale_;               \
        Esum += (float)e_;                                                    \
    }

// ---------------------------------------------------------------------------
// Producer-consumer CTC. One block per batch, 4 waves:
//   waves 1..3: stream every 3rd group of 8 rows (proven per-wave pipeline,
//               measured 1KB/200cyc EACH, proven non-interfering at 2 waves),
//               compute q + per-row z-denominator, publish q rows via LDS ring.
//   wave 0:     alpha recursion consuming q from LDS — no global loads, no
//               exp on the serial chain.
// Aggregate producer rate ~3KB/200cyc > consumer need ~1KB/40cyc bound.
// ---------------------------------------------------------------------------
__global__ void __launch_bounds__(256, 1) ctc_pc_kernel(
        const float* __restrict__ attn,
        const int* __restrict__ text_lens,
        const int* __restrict__ mel_lens,
        float* __restrict__ out) {
    __shared__ float ring[RING_GRPS * 8 * 256];  // 96 KB: q rows, 1KB each
    __shared__ int ready[RING_GRPS];             // slot -> group id + 1
    __shared__ int cons_done;                    // consumed group count
    __shared__ float sal[512];
    __shared__ float zparts[3];

    int b = blockIdx.x;
    int wid = threadIdx.x >> 6;
    int lane = threadIdx.x & 63;
    int L = text_lens[b];
    int n_t = mel_lens[b];
    const char* pbase = (const char*)(attn + (size_t)b * Tn * Un);
    int G = (n_t + 7) >> 3;  // number of 8-row groups

    if (threadIdx.x < RING_GRPS) ready[threadIdx.x] = 0;
    if (threadIdx.x == RING_GRPS) cons_done = 0;
    __syncthreads();

    // per-lane safe byte offsets within a 1000B row (8B aligned, never OOB):
    // lane62 hi aliases lo (cols 250/251 always masked since L<=250),
    // lane63 reads col 0 (all its states masked).
    int voff_lo = lane * 16, voff_hi = lane * 16 + 8;
    if (lane == 62) { voff_lo = 992; voff_hi = 992; }
    if (lane == 63) { voff_lo = 0;   voff_hi = 0;   }
    int c0 = lane * 4;
    float bias0 = (c0 + 0 < L) ? 0.0f : -1000000.0f;
    float bias1 = (c0 + 1 < L) ? 0.0f : -1000000.0f;
    float bias2 = (c0 + 2 < L) ? 0.0f : -1000000.0f;
    float bias3 = (c0 + 3 < L) ? 0.0f : -1000000.0f;

    const float QB = 0.36787944117144233f;  // e^-1 (blank, unnormalized)
    float Esum = 0.0f;                      // consumer-wave renorm exponent

    if (wid == 0) {
        // ------------------------- consumer -------------------------
        float a0 = (lane == 0) ? 1.0f : 0.0f;
        float a1 = 0.0f, a2 = 0.0f, a3 = 0.0f, a4 = 0.0f, a5 = 0.0f,
              a6 = 0.0f, a7 = 0.0f;
        for (int g = 0; g < G; ++g) {
            int s = g % RING_GRPS;
            while (__hip_atomic_load(&ready[s], __ATOMIC_ACQUIRE,
                       __HIP_MEMORY_SCOPE_WORKGROUP) != g + 1)
                __builtin_amdgcn_s_sleep(1);
            __builtin_amdgcn_sched_barrier(0);  // keep ds_reads below the wait
            const float* rb_ = &ring[(size_t)s * 2048 + lane * 4];
            int base_ = 8 * g;
            if (base_ + 0 < n_t) CSTEP(0);
            if (base_ + 1 < n_t) CSTEP(1);
            if (base_ + 2 < n_t) CSTEP(2);
            if (base_ + 3 < n_t) CSTEP(3);
            if (base_ + 4 < n_t) CSTEP(4);
            if (base_ + 5 < n_t) CSTEP(5);
            if (base_ + 6 < n_t) CSTEP(6);
            if (base_ + 7 < n_t) CSTEP(7);
            RENORM();  // every <=8 steps, exact pow2 strip (proven cadence)
            __hip_atomic_store(&cons_done, g + 1, __ATOMIC_RELEASE,
                               __HIP_MEMORY_SCOPE_WORKGROUP);
        }
        sal[lane * 8 + 0] = a0;
        sal[lane * 8 + 1] = a1;
        sal[lane * 8 + 2] = a2;
        sal[lane * 8 + 3] = a3;
        sal[lane * 8 + 4] = a4;
        sal[lane * 8 + 5] = a5;
        sal[lane * 8 + 6] = a6;
        sal[lane * 8 + 7] = a7;
    } else {
        // ------------------------- producer -------------------------
        float zacc = 0.0f;
        v2f lo[16], hi[16];
        int last = n_t - 1;
        int g = wid - 1;                       // first owned group
        int ng = (G - (wid - 1) + 2) / 3;      // number of owned groups (>=1)

        // prologue: slots 0..15 <- its first two groups (rows 8g+j, 8(g+3)+j)
#pragma unroll
        for (int j = 0; j < 16; ++j) {
            int r0_ = 8 * g + 24 * (j >> 3) + (j & 7);
            PREFILL(j, r0_);
        }
        int gk = 0;
        while (true) {
            PGRP(0);                           // slots 0-7
            ++gk; g += 3; if (gk == ng) break;
            PGRP(8);                           // slots 8-15
            ++gk; g += 3; if (gk == ng) break;
        }
        asm volatile("s_waitcnt vmcnt(0)" ::: "memory");  // drain prefetches
        if (lane == 0) zparts[wid - 1] = zacc;  // zacc is wave-uniform
    }

    __syncthreads();  // convergent: each of the 4 waves arrives exactly once

    if (threadIdx.x == 0) {
        float zs = zparts[0] + zparts[1] + zparts[2];
        float ssum = sal[2 * L] + sal[2 * L - 1];
        float fin = (log2fast(ssum) + Esum - zs) * LN2;
        float loss = (ssum <= 0.0f) ? 0.0f : (-fin / (float)L);
        atomicAdd(out, loss * (1.0f / (float)Bn));
    }
}

extern "C" void kernel_launch(void* const* d_in, const int* in_sizes, int n_in,
                              void* d_out, int out_size, void* d_ws, size_t ws_size,
                              hipStream_t stream) {
    const float* attn = (const float*)d_in[0];
    const int* text_lens = (const int*)d_in[1];
    const int* mel_lens = (const int*)d_in[2];
    float* out = (float*)d_out;

    // zero the scalar accumulator (stream-ordered; validated under capture)
    hipMemsetAsync(out, 0, sizeof(float), stream);
    ctc_pc_kernel<<<Bn, 256, 0, stream>>>(attn, text_lens, mel_lens, out);
}